// Round 4
// baseline (424.073 us; speedup 1.0000x reference)
//
#include <hip/hip_runtime.h>
#include <stdint.h>

#define N_TOK  16384
#define EMB    512
#define NEMB   2048
#define NCHUNK 32            // 64 templates per chunk
#define CWIN   1.5e-3f       // flag window: >= 2*grid(6.1e-5) + 2*bf16err(4e-4) w/ margin

typedef __attribute__((ext_vector_type(8))) short s16x8;
typedef __attribute__((ext_vector_type(4))) float f32x4;

__device__ __forceinline__ unsigned short f2bf(float f) {   // RNE f32 -> bf16
  unsigned u = __float_as_uint(f);
  u += 0x7fffu + ((u >> 16) & 1u);
  return (unsigned short)(u >> 16);
}

// numpy pairwise_sum emulation for sum(x*x) over 512 contiguous f32:
// 512 -> 256+256 -> four 128-blocks; each 128-block: 8 sequential accumulators
// combined ((r0+r1)+(r2+r3))+((r4+r5)+(r6+r7)); blocks: (B0+B1)+(B2+B3).
// Executed by one wave; lanes>=32 mirror lanes 0..31. Exact on all lanes.
__device__ __forceinline__ float pairwise512_sq(const float* se, int lane) {
  int l = lane & 31;
  int b = l >> 3, j = l & 7;
  const float* base = se + b * 128 + j;
  float x = base[0];
  float r = __fmul_rn(x, x);
#pragma unroll
  for (int k = 1; k < 16; ++k) {
    float y = base[8 * k];
    r = __fadd_rn(r, __fmul_rn(y, y));
  }
  r = __fadd_rn(r, __shfl_xor(r, 1));    // (r_j + r_{j^1})  — IEEE add commutative
  r = __fadd_rn(r, __shfl_xor(r, 2));
  r = __fadd_rn(r, __shfl_xor(r, 4));    // = B_b
  r = __fadd_rn(r, __shfl_xor(r, 8));    // B0+B1 / B2+B3
  r = __fadd_rn(r, __shfl_xor(r, 16));   // (B0+B1)+(B2+B3)
  return r;
}

// ---------- kernel 1: templat -> bf16 thi + numpy-exact t_sq (f32) ----------
__global__ void prep_t_kernel(const float* __restrict__ tmp,
                              unsigned short* __restrict__ thi, float* __restrict__ tsq) {
  __shared__ float se[EMB];
  int m = blockIdx.x, lane = threadIdx.x;                    // 64 lanes
  const float4* p = (const float4*)(tmp + (size_t)m * EMB) + lane * 2;
  float4 v0 = p[0], v1 = p[1];
  float f[8] = {v0.x, v0.y, v0.z, v0.w, v1.x, v1.y, v1.z, v1.w};
  unsigned h[8];
#pragma unroll
  for (int i = 0; i < 8; ++i) { h[i] = f2bf(f[i]); se[lane * 8 + i] = f[i]; }
  uint4 packed = { h[0] | (h[1] << 16), h[2] | (h[3] << 16),
                   h[4] | (h[5] << 16), h[6] | (h[7] << 16) };
  ((uint4*)(thi + (size_t)m * EMB))[lane] = packed;
  __syncthreads();
  float s = pairwise512_sq(se, lane);
  if (lane == 0) tsq[m] = s;
}

// ---------- kernel 1b: numpy-exact e_sq (f32), one wave per token ----------
__global__ __launch_bounds__(256) void esq_kernel(const float* __restrict__ enc,
                                                  float* __restrict__ esq) {
  __shared__ float se[4][EMB];
  int wave = threadIdx.x >> 6, lane = threadIdx.x & 63;
  int token = blockIdx.x * 4 + wave;
  const float4* p = (const float4*)(enc + (size_t)token * EMB);
  ((float4*)se[wave])[lane]      = p[lane];
  ((float4*)se[wave])[lane + 64] = p[lane + 64];
  __syncthreads();
  float s = pairwise512_sq(se[wave], lane);
  if (lane == 0) esq[token] = s;
}

// ---------- kernel 2: bf16 MFMA scores, best/second/argmin + chunk minima ----------
__global__ __launch_bounds__(256, 2) void score_kernel(
    const float* __restrict__ enc, const unsigned short* __restrict__ thi,
    const float* __restrict__ tsq, float* __restrict__ cmins,
    int* __restrict__ bestIdx2, float* __restrict__ best2, float* __restrict__ second2) {
  __shared__ uint4 sB[4096];                    // 64 KB: (t*16+ks)*64 + lane
  const int tid = threadIdx.x, wave = tid >> 6, lane = tid & 63;
  const int q = lane >> 4, r = lane & 15;
  const int tb = (blockIdx.x >> 1) * 64, half = blockIdx.x & 1;

  s16x8 a[16];
  {
    const float4* ap = (const float4*)(enc + (size_t)(tb + wave * 16 + r) * EMB + q * 8);
#pragma unroll
    for (int ks = 0; ks < 16; ++ks) {
      float4 x = ap[ks * 8], y = ap[ks * 8 + 1];
      s16x8 t;
      t[0] = (short)f2bf(x.x); t[1] = (short)f2bf(x.y);
      t[2] = (short)f2bf(x.z); t[3] = (short)f2bf(x.w);
      t[4] = (short)f2bf(y.x); t[5] = (short)f2bf(y.y);
      t[6] = (short)f2bf(y.z); t[7] = (short)f2bf(y.w);
      a[ks] = t;
    }
  }

  float best[4], second[4]; int bidx[4];
#pragma unroll
  for (int i = 0; i < 4; ++i) { best[i] = INFINITY; second[i] = INFINITY; bidx[i] = 0; }

  for (int c = 0; c < 16; ++c) {
    const int mc = half * 1024 + c * 64;
    {
      const uint4* src = (const uint4*)(thi + (size_t)(mc + wave * 16 + r) * EMB + q * 8);
#pragma unroll
      for (int ks = 0; ks < 16; ++ks) sB[(wave * 16 + ks) * 64 + lane] = src[ks * 4];
    }
    __syncthreads();

    f32x4 acc[4];
#pragma unroll
    for (int t = 0; t < 4; ++t) acc[t] = (f32x4){0.f, 0.f, 0.f, 0.f};
#pragma unroll
    for (int ks = 0; ks < 16; ++ks) {
#pragma unroll
      for (int t = 0; t < 4; ++t) {
        s16x8 b = ((const s16x8*)sB)[(t * 16 + ks) * 64 + lane];
        acc[t] = __builtin_amdgcn_mfma_f32_16x16x32_bf16(a[ks], b, acc[t], 0, 0, 0);
      }
    }
    __syncthreads();

    float sc[4][4];
#pragma unroll
    for (int t = 0; t < 4; ++t) {
      const int m = mc + t * 16 + r;
      const float ts = tsq[m];
#pragma unroll
      for (int i = 0; i < 4; ++i) {
        float s = ts - 2.0f * acc[t][i];
        sc[t][i] = s;
        if (s < best[i]) { second[i] = best[i]; best[i] = s; bidx[i] = m; }
        else second[i] = fminf(second[i], s);
      }
    }
#pragma unroll
    for (int i = 0; i < 4; ++i) {
      float v = fminf(fminf(sc[0][i], sc[1][i]), fminf(sc[2][i], sc[3][i]));
#pragma unroll
      for (int mask = 1; mask <= 8; mask <<= 1) v = fminf(v, __shfl_xor(v, mask));
      if (r == 0)
        cmins[(size_t)(tb + wave * 16 + q * 4 + i) * NCHUNK + half * 16 + c] = v;
    }
  }

#pragma unroll
  for (int i = 0; i < 4; ++i) {
#pragma unroll
    for (int mask = 1; mask <= 8; mask <<= 1) {
      float ob = __shfl_xor(best[i], mask);
      float os = __shfl_xor(second[i], mask);
      int   oi = __shfl_xor(bidx[i], mask);
      float hi = fmaxf(best[i], ob);
      if (ob < best[i] || (ob == best[i] && oi < bidx[i])) { best[i] = ob; bidx[i] = oi; }
      second[i] = fminf(fminf(second[i], os), hi);
    }
  }
  if (r == 0) {
#pragma unroll
    for (int i = 0; i < 4; ++i) {
      int token = tb + wave * 16 + q * 4 + i;
      int slot = token * 2 + half;
      bestIdx2[slot] = bidx[i];
      best2[slot]    = best[i];
      second2[slot]  = second[i];
    }
  }
}

// ---------- kernel 3: merge halves, NaN-safe flag ----------
__global__ void merge_kernel(const int* __restrict__ bestIdx2, const float* __restrict__ best2,
                             const float* __restrict__ second2, int* __restrict__ bestIdx,
                             float* __restrict__ bestVal, int* __restrict__ flag) {
  int t = blockIdx.x * blockDim.x + threadIdx.x;
  if (t >= N_TOK) return;
  float b0 = best2[t * 2],    b1 = best2[t * 2 + 1];
  float s0 = second2[t * 2],  s1 = second2[t * 2 + 1];
  int   i0 = bestIdx2[t * 2], i1 = bestIdx2[t * 2 + 1];
  float best; int idx;
  if (b1 < b0 || (b1 == b0 && i1 < i0)) { best = b1; idx = i1; }
  else                                  { best = b0; idx = i0; }
  float second = fminf(fminf(s0, s1), fmaxf(b0, b1));
  bestIdx[t] = idx;
  bestVal[t] = best;
  bool ok = (second - best >= CWIN) && (idx >= 0) && (idx < NEMB) && (best == best);
  flag[t] = ok ? 0 : 1;
}

// ---------- kernel 4: f32-emulated dist over candidate chunks, first-index ties ----------
__global__ __launch_bounds__(256) void refine_kernel(
    const float* __restrict__ enc, const float* __restrict__ tmp,
    const float* __restrict__ esq, const float* __restrict__ tsq,
    const float* __restrict__ cmins, const float* __restrict__ bestVal,
    const int* __restrict__ flag, int* __restrict__ bestIdx) {
  int token = blockIdx.x;
  if (!flag[token]) return;
  __shared__ float se[EMB];
  for (int i = threadIdx.x; i < EMB; i += 256) se[i] = enc[(size_t)token * EMB + i];
  __syncthreads();
  float e2 = esq[token];
  float bv = bestVal[token];
  bool nanCase = !(bv == bv);
  float limit = bv + CWIN;
  int sub = threadIdx.x & 3, row = threadIdx.x >> 2;         // 64 rows x 4 k-slices
  float bd = INFINITY; int bm = NEMB;
  for (int c = 0; c < NCHUNK; ++c) {
    float cm = cmins[(size_t)token * NCHUNK + c];
    bool cand = nanCase || !(cm > limit);                    // NaN cm -> candidate
    if (!cand) continue;                                     // block-uniform
    int m = c * 64 + row;
    const float* trow = tmp + (size_t)m * EMB + sub * 128;
    const float* erow = se + sub * 128;
    double s = 0.0;
    for (int k = 0; k < 128; ++k) s += (double)trow[k] * (double)erow[k];
    s += __shfl_xor(s, 1);
    s += __shfl_xor(s, 2);
    if (sub == 0) {
      // emulate numpy f32: dist = fl32( fl32(e_sq - 2*M) + t_sq ), M = fl32(dot)
      float M  = (float)s;
      float d1 = __fadd_rn(e2, -__fmul_rn(2.0f, M));
      float d2 = __fadd_rn(d1, tsq[m]);
      if (d2 < bd || (d2 == bd && m < bm)) { bd = d2; bm = m; }
    }
  }
  __shared__ float rb[64]; __shared__ int ri[64];
  if (sub == 0) { rb[row] = bd; ri[row] = bm; }
  __syncthreads();
  if (threadIdx.x == 0) {
    float b = rb[0]; int bi = ri[0];
    for (int j = 1; j < 64; ++j)
      if (rb[j] < b || (rb[j] == b && ri[j] < bi)) { b = rb[j]; bi = ri[j]; }
    if (bi < NEMB) bestIdx[token] = bi;
  }
}

// ---------- kernel 5: gather f32 rows + zidx as f32 ----------
__global__ void gather_kernel(const float* __restrict__ tmp, const int* __restrict__ bestIdx,
                              float* __restrict__ out) {
  int token = blockIdx.x * 4 + (threadIdx.x >> 6);
  int lane = threadIdx.x & 63;
  int idx = bestIdx[token];
  idx = idx < 0 ? 0 : (idx > NEMB - 1 ? NEMB - 1 : idx);     // never fault
  const float4* src = (const float4*)(tmp + (size_t)idx * EMB) + lane * 2;
  float4* dst = (float4*)(out + (size_t)token * EMB) + lane * 2;
  dst[0] = src[0];
  dst[1] = src[1];
  if (lane == 0) out[(size_t)N_TOK * EMB + token] = (float)idx;
}

extern "C" void kernel_launch(void* const* d_in, const int* in_sizes, int n_in,
                              void* d_out, int out_size, void* d_ws, size_t ws_size,
                              hipStream_t stream) {
  const float* enc = (const float*)d_in[0];
  const float* tmp = (const float*)d_in[1];
  float* out = (float*)d_out;
  char* ws = (char*)d_ws;
  unsigned short* thi = (unsigned short*)ws;                 // 2,097,152 B
  float* tsq      = (float*)(ws + 2097152);                  //     8,192 B
  float* esq      = (float*)(ws + 2105344);                  //    65,536 B
  float* best2    = (float*)(ws + 2170880);                  //   131,072 B
  float* second2  = (float*)(ws + 2301952);                  //   131,072 B
  int*   bestIdx2 = (int*)  (ws + 2433024);                  //   131,072 B
  float* cmins    = (float*)(ws + 2564096);                  // 2,097,152 B
  int*   bestIdx  = (int*)  (ws + 4661248);                  //    65,536 B
  float* bestVal  = (float*)(ws + 4726784);                  //    65,536 B
  int*   flag     = (int*)  (ws + 4792320);                  //    65,536 B

  prep_t_kernel<<<NEMB,      64,  0, stream>>>(tmp, thi, tsq);
  esq_kernel   <<<N_TOK/4,   256, 0, stream>>>(enc, esq);
  score_kernel <<<512,       256, 0, stream>>>(enc, thi, tsq, cmins, bestIdx2, best2, second2);
  merge_kernel <<<N_TOK/256, 256, 0, stream>>>(bestIdx2, best2, second2, bestIdx, bestVal, flag);
  refine_kernel<<<N_TOK,     256, 0, stream>>>(enc, tmp, esq, tsq, cmins, bestVal, flag, bestIdx);
  gather_kernel<<<N_TOK/4,   256, 0, stream>>>(tmp, bestIdx, out);
}

// Round 5
// 256.291 us; speedup vs baseline: 1.6547x; 1.6547x over previous
//
#include <hip/hip_runtime.h>
#include <stdint.h>

#define N_TOK  16384
#define EMB    512
#define NEMB   2048
#define NCHUNK 32            // 64 templates per chunk
#define CWIN   2.5e-4f       // 1.22e-4 ref-f32-grid + ~13 sigma bf16 score noise
#define WCAP   524288        // worst case: all tokens x all chunks

typedef __attribute__((ext_vector_type(8))) short s16x8;
typedef __attribute__((ext_vector_type(4))) float f32x4;

__device__ __forceinline__ unsigned short f2bf(float f) {   // RNE f32 -> bf16
  unsigned u = __float_as_uint(f);
  u += 0x7fffu + ((u >> 16) & 1u);
  return (unsigned short)(u >> 16);
}

// numpy pairwise_sum emulation for sum(x*x) over 512 contiguous f32.
__device__ __forceinline__ float pairwise512_sq(const float* se, int lane) {
  int l = lane & 31;
  int b = l >> 3, j = l & 7;
  const float* base = se + b * 128 + j;
  float x = base[0];
  float r = __fmul_rn(x, x);
#pragma unroll
  for (int k = 1; k < 16; ++k) {
    float y = base[8 * k];
    r = __fadd_rn(r, __fmul_rn(y, y));
  }
  r = __fadd_rn(r, __shfl_xor(r, 1));
  r = __fadd_rn(r, __shfl_xor(r, 2));
  r = __fadd_rn(r, __shfl_xor(r, 4));
  r = __fadd_rn(r, __shfl_xor(r, 8));
  r = __fadd_rn(r, __shfl_xor(r, 16));
  return r;
}

// ---------- kernel 1: templat -> bf16 thi + numpy-exact t_sq ----------
__global__ void prep_t_kernel(const float* __restrict__ tmp,
                              unsigned short* __restrict__ thi, float* __restrict__ tsq) {
  __shared__ float se[EMB];
  int m = blockIdx.x, lane = threadIdx.x;                    // 64 lanes
  const float4* p = (const float4*)(tmp + (size_t)m * EMB) + lane * 2;
  float4 v0 = p[0], v1 = p[1];
  float f[8] = {v0.x, v0.y, v0.z, v0.w, v1.x, v1.y, v1.z, v1.w};
  unsigned h[8];
#pragma unroll
  for (int i = 0; i < 8; ++i) { h[i] = f2bf(f[i]); se[lane * 8 + i] = f[i]; }
  uint4 packed = { h[0] | (h[1] << 16), h[2] | (h[3] << 16),
                   h[4] | (h[5] << 16), h[6] | (h[7] << 16) };
  ((uint4*)(thi + (size_t)m * EMB))[lane] = packed;
  __syncthreads();
  float s = pairwise512_sq(se, lane);
  if (lane == 0) tsq[m] = s;
}

// ---------- kernel 1b: numpy-exact e_sq, one wave per token ----------
__global__ __launch_bounds__(256) void esq_kernel(const float* __restrict__ enc,
                                                  float* __restrict__ esq) {
  __shared__ float se[4][EMB];
  int wave = threadIdx.x >> 6, lane = threadIdx.x & 63;
  int token = blockIdx.x * 4 + wave;
  const float4* p = (const float4*)(enc + (size_t)token * EMB);
  ((float4*)se[wave])[lane]      = p[lane];
  ((float4*)se[wave])[lane + 64] = p[lane + 64];
  __syncthreads();
  float s = pairwise512_sq(se[wave], lane);
  if (lane == 0) esq[token] = s;
}

// ---------- kernel 2: bf16 MFMA scores, best/second/argmin + chunk minima ----------
__global__ __launch_bounds__(256, 2) void score_kernel(
    const float* __restrict__ enc, const unsigned short* __restrict__ thi,
    const float* __restrict__ tsq, float* __restrict__ cmins,
    int* __restrict__ bestIdx2, float* __restrict__ best2, float* __restrict__ second2) {
  __shared__ uint4 sB[4096];                    // 64 KB: (t*16+ks)*64 + lane
  const int tid = threadIdx.x, wave = tid >> 6, lane = tid & 63;
  const int q = lane >> 4, r = lane & 15;
  const int tb = (blockIdx.x >> 1) * 64, half = blockIdx.x & 1;

  s16x8 a[16];
  {
    const float4* ap = (const float4*)(enc + (size_t)(tb + wave * 16 + r) * EMB + q * 8);
#pragma unroll
    for (int ks = 0; ks < 16; ++ks) {
      float4 x = ap[ks * 8], y = ap[ks * 8 + 1];
      s16x8 t;
      t[0] = (short)f2bf(x.x); t[1] = (short)f2bf(x.y);
      t[2] = (short)f2bf(x.z); t[3] = (short)f2bf(x.w);
      t[4] = (short)f2bf(y.x); t[5] = (short)f2bf(y.y);
      t[6] = (short)f2bf(y.z); t[7] = (short)f2bf(y.w);
      a[ks] = t;
    }
  }

  float best[4], second[4]; int bidx[4];
#pragma unroll
  for (int i = 0; i < 4; ++i) { best[i] = INFINITY; second[i] = INFINITY; bidx[i] = 0; }

  for (int c = 0; c < 16; ++c) {
    const int mc = half * 1024 + c * 64;
    {
      const uint4* src = (const uint4*)(thi + (size_t)(mc + wave * 16 + r) * EMB + q * 8);
#pragma unroll
      for (int ks = 0; ks < 16; ++ks) sB[(wave * 16 + ks) * 64 + lane] = src[ks * 4];
    }
    __syncthreads();

    f32x4 acc[4];
#pragma unroll
    for (int t = 0; t < 4; ++t) acc[t] = (f32x4){0.f, 0.f, 0.f, 0.f};
#pragma unroll
    for (int ks = 0; ks < 16; ++ks) {
#pragma unroll
      for (int t = 0; t < 4; ++t) {
        s16x8 b = ((const s16x8*)sB)[(t * 16 + ks) * 64 + lane];
        acc[t] = __builtin_amdgcn_mfma_f32_16x16x32_bf16(a[ks], b, acc[t], 0, 0, 0);
      }
    }
    __syncthreads();

    float sc[4][4];
#pragma unroll
    for (int t = 0; t < 4; ++t) {
      const int m = mc + t * 16 + r;
      const float ts = tsq[m];
#pragma unroll
      for (int i = 0; i < 4; ++i) {
        float s = ts - 2.0f * acc[t][i];
        sc[t][i] = s;
        if (s < best[i]) { second[i] = best[i]; best[i] = s; bidx[i] = m; }
        else second[i] = fminf(second[i], s);
      }
    }
#pragma unroll
    for (int i = 0; i < 4; ++i) {
      float v = fminf(fminf(sc[0][i], sc[1][i]), fminf(sc[2][i], sc[3][i]));
#pragma unroll
      for (int mask = 1; mask <= 8; mask <<= 1) v = fminf(v, __shfl_xor(v, mask));
      if (r == 0)
        cmins[(size_t)(tb + wave * 16 + q * 4 + i) * NCHUNK + half * 16 + c] = v;
    }
  }

#pragma unroll
  for (int i = 0; i < 4; ++i) {
#pragma unroll
    for (int mask = 1; mask <= 8; mask <<= 1) {
      float ob = __shfl_xor(best[i], mask);
      float os = __shfl_xor(second[i], mask);
      int   oi = __shfl_xor(bidx[i], mask);
      float hi = fmaxf(best[i], ob);
      if (ob < best[i] || (ob == best[i] && oi < bidx[i])) { best[i] = ob; bidx[i] = oi; }
      second[i] = fminf(fminf(second[i], os), hi);
    }
  }
  if (r == 0) {
#pragma unroll
    for (int i = 0; i < 4; ++i) {
      int token = tb + wave * 16 + q * 4 + i;
      int slot = token * 2 + half;
      bestIdx2[slot] = bidx[i];
      best2[slot]    = best[i];
      second2[slot]  = second[i];
    }
  }
}

// ---------- kernel 3: merge halves, flag, build compacted (token,chunk) worklist ----------
__global__ void merge_kernel(const int* __restrict__ bestIdx2, const float* __restrict__ best2,
                             const float* __restrict__ second2, const float* __restrict__ cmins,
                             int* __restrict__ bestIdx, int* __restrict__ flag,
                             int* __restrict__ work, int* __restrict__ wcount) {
  int t = blockIdx.x * blockDim.x + threadIdx.x;
  if (t >= N_TOK) return;
  float b0 = best2[t * 2],    b1 = best2[t * 2 + 1];
  float s0 = second2[t * 2],  s1 = second2[t * 2 + 1];
  int   i0 = bestIdx2[t * 2], i1 = bestIdx2[t * 2 + 1];
  float best; int idx;
  if (b1 < b0 || (b1 == b0 && i1 < i0)) { best = b1; idx = i1; }
  else                                  { best = b0; idx = i0; }
  float second = fminf(fminf(s0, s1), fmaxf(b0, b1));
  bestIdx[t] = idx;
  bool ok = (second - best >= CWIN) && (idx >= 0) && (idx < NEMB) && (best == best);
  flag[t] = ok ? 0 : 1;
  if (!ok) {
    bool nanCase = !(best == best);
    float limit = best + CWIN;
    for (int c = 0; c < NCHUNK; ++c) {
      float cm = cmins[(size_t)t * NCHUNK + c];
      if (nanCase || !(cm > limit)) {               // NaN cm -> candidate
        int pos = atomicAdd(wcount, 1);
        if (pos < WCAP) work[pos] = t * NCHUNK + c;
      }
    }
  }
}

// ---------- kernel 4: coalesced f32-emulated rescan over worklist pairs ----------
// One block per (token,chunk) pair (grid-stride). Wave wv handles rows wv+4j.
// Winner via atomicMin on key = (f32bits(dist)<<32)|m  (dist>0 -> monotone).
__global__ __launch_bounds__(256) void refine_kernel(
    const float* __restrict__ enc, const float* __restrict__ tmp,
    const float* __restrict__ esq, const float* __restrict__ tsq,
    const int* __restrict__ work, const int* __restrict__ wcount,
    unsigned long long* __restrict__ rkey) {
  int total = *wcount; if (total > WCAP) total = WCAP;
  __shared__ float se[EMB];
  const int wv = threadIdx.x >> 6, lane = threadIdx.x & 63;
  for (int p = blockIdx.x; p < total; p += gridDim.x) {
    __syncthreads();                                // protect se across iterations
    int item = work[p];
    int token = item / NCHUNK, c = item % NCHUNK;
    const float4* erow = (const float4*)(enc + (size_t)token * EMB);
    for (int i = threadIdx.x; i < 128; i += 256) ((float4*)se)[i] = erow[i];
    __syncthreads();
    float e2 = esq[token];
    unsigned long long lkey = ~0ULL;
#pragma unroll
    for (int j = 0; j < 16; ++j) {
      int m = c * 64 + wv + j * 4;
      const float4* trow = (const float4*)(tmp + (size_t)m * EMB);
      float4 a0 = trow[lane], a1 = trow[lane + 64];          // lane*16B: coalesced
      float4 b0 = ((const float4*)se)[lane], b1 = ((const float4*)se)[lane + 64];
      double s = (double)a0.x * b0.x + (double)a0.y * b0.y
               + (double)a0.z * b0.z + (double)a0.w * b0.w
               + (double)a1.x * b1.x + (double)a1.y * b1.y
               + (double)a1.z * b1.z + (double)a1.w * b1.w;
#pragma unroll
      for (int mask = 1; mask < 64; mask <<= 1) s += __shfl_xor(s, mask);
      if (lane == 0) {
        float M  = (float)s;                                 // fl32(f64 dot)
        float d1 = __fadd_rn(e2, -__fmul_rn(2.0f, M));
        float d2 = __fadd_rn(d1, tsq[m]);
        unsigned long long key =
            ((unsigned long long)__float_as_uint(d2) << 32) | (unsigned)m;
        if (key < lkey) lkey = key;
      }
    }
    if (lane == 0 && lkey != ~0ULL) atomicMin(&rkey[token], lkey);
  }
}

// ---------- kernel 5: gather f32 rows + zidx as f32 ----------
__global__ void gather_kernel(const float* __restrict__ tmp, const int* __restrict__ bestIdx,
                              const int* __restrict__ flag,
                              const unsigned long long* __restrict__ rkey,
                              float* __restrict__ out) {
  int token = blockIdx.x * 4 + (threadIdx.x >> 6);
  int lane = threadIdx.x & 63;
  int idx = flag[token] ? (int)(unsigned)(rkey[token] & 0xffffffffULL) : bestIdx[token];
  idx = idx < 0 ? 0 : (idx > NEMB - 1 ? NEMB - 1 : idx);     // never fault
  const float4* src = (const float4*)(tmp + (size_t)idx * EMB) + lane * 2;
  float4* dst = (float4*)(out + (size_t)token * EMB) + lane * 2;
  dst[0] = src[0];
  dst[1] = src[1];
  if (lane == 0) out[(size_t)N_TOK * EMB + token] = (float)idx;
}

extern "C" void kernel_launch(void* const* d_in, const int* in_sizes, int n_in,
                              void* d_out, int out_size, void* d_ws, size_t ws_size,
                              hipStream_t stream) {
  const float* enc = (const float*)d_in[0];
  const float* tmp = (const float*)d_in[1];
  float* out = (float*)d_out;
  char* ws = (char*)d_ws;
  unsigned short* thi = (unsigned short*)ws;                 // 2,097,152 B
  float* tsq      = (float*)(ws + 2097152);                  //     8,192 B
  float* esq      = (float*)(ws + 2105344);                  //    65,536 B
  float* best2    = (float*)(ws + 2170880);                  //   131,072 B
  float* second2  = (float*)(ws + 2301952);                  //   131,072 B
  int*   bestIdx2 = (int*)  (ws + 2433024);                  //   131,072 B
  float* cmins    = (float*)(ws + 2564096);                  // 2,097,152 B
  int*   bestIdx  = (int*)  (ws + 4661248);                  //    65,536 B
  int*   flag     = (int*)  (ws + 4726784);                  //    65,536 B
  unsigned long long* rkey = (unsigned long long*)(ws + 4792320); // 131,072 B
  int*   wcount   = (int*)  (ws + 4923392);                  //        64 B
  int*   work     = (int*)  (ws + 4923456);                  // 2,097,152 B

  hipMemsetAsync(wcount, 0,    64,     stream);
  hipMemsetAsync(rkey,   0xFF, 131072, stream);

  prep_t_kernel<<<NEMB,      64,  0, stream>>>(tmp, thi, tsq);
  esq_kernel   <<<N_TOK/4,   256, 0, stream>>>(enc, esq);
  score_kernel <<<512,       256, 0, stream>>>(enc, thi, tsq, cmins, bestIdx2, best2, second2);
  merge_kernel <<<N_TOK/256, 256, 0, stream>>>(bestIdx2, best2, second2, cmins,
                                               bestIdx, flag, work, wcount);
  refine_kernel<<<1024,      256, 0, stream>>>(enc, tmp, esq, tsq, work, wcount, rkey);
  gather_kernel<<<N_TOK/4,   256, 0, stream>>>(tmp, bestIdx, flag, rkey, out);
}